// Round 3
// baseline (3259.206 us; speedup 1.0000x reference)
//
#include <hip/hip_runtime.h>

#define DI __device__ __forceinline__
DI float silu_f(float x){ return x * (1.0f/(1.0f+__expf(-x))); }

// ---------------------------------------------------------------------------
// Direct conv, NHWC input, HWIO weights. Thread = NPIX pixels x 4 co.
// G>1 splits the K dimension: KYS=false -> ci-split (CLEN=CIN/G),
// KYS=true -> ky-row split. Group index in LOW bits of blockIdx so the
// XCD round-robin (block%8) pins each XCD to one weight slice (L2-resident).
// Partials (BIAS=false) are written at out + g*total*COUT.
// ---------------------------------------------------------------------------
template<int KH,int KW,int STRIDE,int PAD,int CIN,int COUT,int NPIX,
         bool ACT,bool BIAS,int G,bool KYS>
__global__ __launch_bounds__(256) void conv_k(
    const float* __restrict__ in, const float* __restrict__ w,
    const float* __restrict__ bias, float* __restrict__ out,
    int N,int H,int W,int OH,int OW)
{
  constexpr int COQ  = COUT/4;
  constexpr int CLEN = KYS ? CIN : CIN/G;
  constexpr int GSH  = (G==8)?3:(G==4)?2:(G==2)?1:0;
  constexpr int KYB  = (KH+G-1)/G;
  static_assert(G==1||G==2||G==4||G==8, "G");
  static_assert(CLEN==3 || (CLEN%4)==0, "ci");

  const int g  = blockIdx.x & (G-1);
  const int bx = blockIdx.x >> GSH;
  const int total = N*OH*OW;
  if (G>1) out += (size_t)g * total * COUT;
  const int ky_lo = KYS ? g*KYB : 0;
  const int ky_hi = KYS ? ((g*KYB+KYB) < KH ? g*KYB+KYB : KH) : KH;
  const int ci_off = KYS ? 0 : g*CLEN;

  int idx = bx*256 + threadIdx.x;
  int cq = idx % COQ;
  int pg = idx / COQ;
  int co = cq*4;
  int p0 = pg*NPIX;
  if (p0 >= total) return;

  float acc[NPIX][4] = {};
  int iy0[NPIX], ix0[NPIX]; const float* base[NPIX]; bool pv[NPIX];
#pragma unroll
  for (int t=0;t<NPIX;t++){
    int p=p0+t; pv[t]=(p<total); int pp=pv[t]?p:p0;
    int ox=pp%OW; int r=pp/OW; int oy=r%OH; int n=r/OH;
    iy0[t]=oy*STRIDE-PAD; ix0[t]=ox*STRIDE-PAD;
    base[t]=in+(size_t)n*H*W*CIN + ci_off;
  }

  for (int ky=ky_lo; ky<ky_hi; ky++){
    for (int kx=0; kx<KW; kx++){
      const float* wp = w + ((size_t)(ky*KW+kx)*CIN + ci_off)*COUT + co;
      const float* ip[NPIX]; bool ok[NPIX];
#pragma unroll
      for (int t=0;t<NPIX;t++){
        int iy=iy0[t]+ky, ix=ix0[t]+kx;
        ok[t]=pv[t] && iy>=0 && iy<H && ix>=0 && ix<W;
        ip[t]=base[t]+(size_t)(iy*W+ix)*CIN;
      }
      if constexpr (CLEN==3){
        float wv[3][4];
        *(float4*)wv[0]=*(const float4*)(wp);
        *(float4*)wv[1]=*(const float4*)(wp+COUT);
        *(float4*)wv[2]=*(const float4*)(wp+2*COUT);
#pragma unroll
        for (int t=0;t<NPIX;t++){
          float v0=ok[t]?ip[t][0]:0.f;
          float v1=ok[t]?ip[t][1]:0.f;
          float v2=ok[t]?ip[t][2]:0.f;
#pragma unroll
          for (int j=0;j<4;j++)
            acc[t][j]=fmaf(v0,wv[0][j],fmaf(v1,wv[1][j],fmaf(v2,wv[2][j],acc[t][j])));
        }
      } else {
#pragma unroll 2
        for (int ci=0; ci<CLEN; ci+=4){
          float wv[4][4];
#pragma unroll
          for (int r=0;r<4;r++)
            *(float4*)wv[r] = *(const float4*)(wp + (ci+r)*COUT);
#pragma unroll
          for (int t=0;t<NPIX;t++){
            float va[4];
            *(float4*)va = ok[t] ? *(const float4*)(ip[t]+ci)
                                 : make_float4(0.f,0.f,0.f,0.f);
#pragma unroll
            for (int r=0;r<4;r++)
#pragma unroll
              for (int j=0;j<4;j++)
                acc[t][j]=fmaf(va[r],wv[r][j],acc[t][j]);
          }
        }
      }
    }
  }

  float bv[4]={0.f,0.f,0.f,0.f};
  if constexpr (BIAS) *(float4*)bv = *(const float4*)(bias+co);
#pragma unroll
  for (int t=0;t<NPIX;t++) if (pv[t]){
    float o[4];
#pragma unroll
    for (int j=0;j<4;j++){
      float v = acc[t][j]+bv[j];
      o[j] = ACT ? silu_f(v) : v;
    }
    *(float4*)(out + (size_t)(p0+t)*COUT + co) = *(float4*)o;
  }
}

// ---------------------------------------------------------------------------
// reduce G partials (stride n) + bias + optional silu, float4 per thread.
// ---------------------------------------------------------------------------
template<int G,int COUT,bool ACT>
__global__ __launch_bounds__(256) void reduce_k(
    const float* __restrict__ p, const float* __restrict__ bias,
    float* __restrict__ out, int n)
{
  int i = (blockIdx.x*256+threadIdx.x)*4;
  if (i>=n) return;
  float a[4]; *(float4*)a = *(const float4*)(p+i);
#pragma unroll
  for (int g=1; g<G; g++){
    float b[4]; *(float4*)b = *(const float4*)(p+(size_t)g*n+i);
#pragma unroll
    for (int j=0;j<4;j++) a[j]+=b[j];
  }
  float bv[4]; *(float4*)bv = *(const float4*)(bias + (i % COUT));
#pragma unroll
  for (int j=0;j<4;j++){
    float v=a[j]+bv[j];
    a[j] = ACT ? silu_f(v) : v;
  }
  *(float4*)(out+i) = *(float4*)a;
}

// ---------------------------------------------------------------------------
// conv_transpose 5x5 stride 2 SAME (verified r0 mapping). parity = b&3,
// ci-group = (b>>2)&(G-1), spatial = b>>(2+GSH). DIRECT: bias+silu in-kernel.
// ---------------------------------------------------------------------------
template<int CIN,int COUT,int NPIX,int G,bool DIRECT>
__global__ __launch_bounds__(256) void tconv_k(
    const float* __restrict__ in, const float* __restrict__ w,
    const float* __restrict__ bias, float* __restrict__ out,
    int N,int H,int W,int OH,int OW)
{
  constexpr int COQ  = COUT/4;
  constexpr int CLEN = CIN/G;
  constexpr int GSH  = (G==8)?3:(G==4)?2:(G==2)?1:0;
  const int par = blockIdx.x & 3;
  const int py = par>>1, px = par&1;
  const int g  = (blockIdx.x>>2) & (G-1);
  const int bx = blockIdx.x >> (2+GSH);
  const int NKY = py?3:2, NKX = px?3:2;
  const int OHh=OH>>1, OWh=OW>>1;
  const int total = N*OHh*OWh;
  if (G>1) out += (size_t)g * N*OH*OW*COUT;

  int idx = bx*256 + threadIdx.x;
  int cq = idx % COQ;
  int pg = idx / COQ;
  int co = cq*4;
  int p0 = pg*NPIX;
  if (p0 >= total) return;

  float acc[NPIX][4] = {};
  int yy[NPIX], xx[NPIX], nn[NPIX]; const float* base[NPIX]; bool pv[NPIX];
#pragma unroll
  for (int t=0;t<NPIX;t++){
    int p=p0+t; pv[t]=(p<total); int pp=pv[t]?p:p0;
    xx[t]=pp%OWh; int r=pp/OWh; yy[t]=r%OHh; nn[t]=r/OHh;
    base[t]=in+(size_t)nn[t]*H*W*CIN + g*CLEN;
  }

  for (int j=0;j<NKY;j++){
    int ky = 2*j + (py?0:1);
    for (int i=0;i<NKX;i++){
      int kx = 2*i + (px?0:1);
      const float* wp = w + ((size_t)(ky*5+kx)*CIN + g*CLEN)*COUT + co;
      const float* ip[NPIX]; bool ok[NPIX];
#pragma unroll
      for (int t=0;t<NPIX;t++){
        int iy=yy[t]+j-1, ix=xx[t]+i-1;
        ok[t]=pv[t] && iy>=0 && iy<H && ix>=0 && ix<W;
        ip[t]=base[t]+(size_t)(iy*W+ix)*CIN;
      }
#pragma unroll 2
      for (int ci=0; ci<CLEN; ci+=4){
        float wv[4][4];
#pragma unroll
        for (int r=0;r<4;r++)
          *(float4*)wv[r] = *(const float4*)(wp + (ci+r)*COUT);
#pragma unroll
        for (int t=0;t<NPIX;t++){
          float va[4];
          *(float4*)va = ok[t] ? *(const float4*)(ip[t]+ci)
                               : make_float4(0.f,0.f,0.f,0.f);
#pragma unroll
          for (int r=0;r<4;r++)
#pragma unroll
            for (int jj=0;jj<4;jj++)
              acc[t][jj]=fmaf(va[r],wv[r][jj],acc[t][jj]);
        }
      }
    }
  }

  float bv[4]={0.f,0.f,0.f,0.f};
  if constexpr (DIRECT) *(float4*)bv = *(const float4*)(bias+co);
#pragma unroll
  for (int t=0;t<NPIX;t++) if (pv[t]){
    float o[4];
#pragma unroll
    for (int jj=0;jj<4;jj++){
      float v = acc[t][jj]+bv[jj];
      o[jj] = DIRECT ? silu_f(v) : v;
    }
    *(float4*)(out + (((size_t)nn[t]*OH + (2*yy[t]+py))*OW + (2*xx[t]+px))*COUT + co) = *(float4*)o;
  }
}

// ---------------------------------------------------------------------------
// VQ fused with conv3c G-partial reduction + bias. One wave per latent.
// ---------------------------------------------------------------------------
template<int G>
__global__ __launch_bounds__(256) void vq_k(
    const float* __restrict__ p, const float* __restrict__ bias,
    const float* __restrict__ cb, float* __restrict__ q, int NLat)
{
  __shared__ float slat[4][128];
  int wave = threadIdx.x >> 6;
  int lane = threadIdx.x & 63;
  int l = blockIdx.x*4 + wave;
  if (l >= NLat) return;
  const size_t stride = (size_t)NLat*128;
  float v0 = bias[lane], v1 = bias[lane+64];
#pragma unroll
  for (int g=0; g<G; g++){
    v0 += p[g*stride + (size_t)l*128 + lane];
    v1 += p[g*stride + (size_t)l*128 + lane + 64];
  }
  slat[wave][lane] = v0;
  slat[wave][lane+64] = v1;

  float bestd = INFINITY; int besti = 0;
  for (int c0=0;c0<256;c0+=64){
    int c = c0 + lane;
    const float* cp = cb + (size_t)c*128;
    float d = 0.f;
#pragma unroll 8
    for (int k=0;k<128;k+=4){
      float4 cv = *reinterpret_cast<const float4*>(cp+k);
      float d0 = slat[wave][k+0]-cv.x;
      float d1 = slat[wave][k+1]-cv.y;
      float d2 = slat[wave][k+2]-cv.z;
      float d3 = slat[wave][k+3]-cv.w;
      d += d0*d0; d += d1*d1; d += d2*d2; d += d3*d3;
    }
    if (d < bestd) { bestd = d; besti = c; }
  }
  for (int off=32; off; off>>=1){
    float od = __shfl_down(bestd, off);
    int   oi = __shfl_down(besti, off);
    if (od < bestd || (od == bestd && oi < besti)) { bestd=od; besti=oi; }
  }
  besti = __shfl(besti, 0);
  const float* cp = cb + (size_t)besti*128;
  float* qp = q + (size_t)l*128;
  qp[lane]    = cp[lane];
  qp[lane+64] = cp[lane+64];
}

// ---------------------------------------------------------------------------
// Final 3x3 conv 32->3 split over ky rows (g = blockIdx%3). Writes partials.
// ---------------------------------------------------------------------------
__global__ __launch_bounds__(256) void conv_last_k(
    const float* __restrict__ in, const float* __restrict__ w,
    float* __restrict__ p, int N,int H,int W)
{
  int g = blockIdx.x % 3;
  int bx = blockIdx.x / 3;
  int pix = bx*256 + threadIdx.x;
  int total = N*H*W;
  if (pix>=total) return;
  int x = pix % W; int r = pix / W; int y = r % H; int n = r / H;
  float a0=0.f, a1=0.f, a2=0.f;
  int iy = y + g - 1;
  if (iy>=0 && iy<H){
    const float* base = in + ((size_t)n*H + iy)*W*32;
    for (int kx=0;kx<3;kx++){
      int ix=x+kx-1; if(ix<0||ix>=W) continue;
      const float* ip = base + (size_t)ix*32;
      const float* wp = w + (size_t)((g*3+kx)*32)*3;
#pragma unroll
      for (int ci=0;ci<32;ci+=4){
        float va[4]; *(float4*)va = *(const float4*)(ip+ci);
        float wv[12];
        *(float4*)(wv+0) = *(const float4*)(wp+ci*3+0);
        *(float4*)(wv+4) = *(const float4*)(wp+ci*3+4);
        *(float4*)(wv+8) = *(const float4*)(wp+ci*3+8);
#pragma unroll
        for (int r2=0;r2<4;r2++){
          a0 = fmaf(va[r2], wv[r2*3+0], a0);
          a1 = fmaf(va[r2], wv[r2*3+1], a1);
          a2 = fmaf(va[r2], wv[r2*3+2], a2);
        }
      }
    }
  }
  float* pp = p + (size_t)g*total*3 + (size_t)pix*3;
  pp[0]=a0; pp[1]=a1; pp[2]=a2;
}

__global__ __launch_bounds__(256) void reduce_last_k(
    const float* __restrict__ p, const float* __restrict__ bias,
    float* __restrict__ out, int n)
{
  int i = (blockIdx.x*256+threadIdx.x)*4;
  if (i>=n) return;
  float a[4]; *(float4*)a = *(const float4*)(p+i);
#pragma unroll
  for (int g=1; g<3; g++){
    float b[4]; *(float4*)b = *(const float4*)(p+(size_t)g*n+i);
#pragma unroll
    for (int j=0;j<4;j++) a[j]+=b[j];
  }
  float o[4];
#pragma unroll
  for (int j=0;j<4;j++) o[j] = a[j] + bias[(i+j)%3];
  *(float4*)(out+i) = *(float4*)o;
}

extern "C" void kernel_launch(void* const* d_in, const int* in_sizes, int n_in,
                              void* d_out, int out_size, void* d_ws, size_t ws_size,
                              hipStream_t stream) {
  const float* x    = (const float*)d_in[0];
  const float* k1   = (const float*)d_in[1];  const float* b1  = (const float*)d_in[2];
  const float* k1c  = (const float*)d_in[3];  const float* b1c = (const float*)d_in[4];
  const float* k2   = (const float*)d_in[5];  const float* b2  = (const float*)d_in[6];
  const float* k2c  = (const float*)d_in[7];  const float* b2c = (const float*)d_in[8];
  const float* k3   = (const float*)d_in[9];  const float* b3  = (const float*)d_in[10];
  const float* k3c  = (const float*)d_in[11]; const float* b3c = (const float*)d_in[12];
  const float* cb   = (const float*)d_in[13];
  const float* tk1  = (const float*)d_in[14]; const float* tb1  = (const float*)d_in[15];
  const float* tk1c = (const float*)d_in[16]; const float* tb1c = (const float*)d_in[17];
  const float* tk2  = (const float*)d_in[18]; const float* tb2  = (const float*)d_in[19];
  const float* tk2c = (const float*)d_in[20]; const float* tb2c = (const float*)d_in[21];
  const float* tk3  = (const float*)d_in[22]; const float* tb3  = (const float*)d_in[23];
  const float* tk3c = (const float*)d_in[24]; const float* tb3c = (const float*)d_in[25];
  float* out = (float*)d_out;

  float* S  = (float*)d_ws;
  float* W0 = S;                 // [0 .. 1M) floats
  float* W1 = S + 1048576;       // [1M .. 2M)
  float* P  = S + 2097152;       // [2M .. 6M)  partials / big activation
  // total ws use: 6M floats = 24 MB

  dim3 blk(256);
  // ---- encoder ----
  // conv1 11x11 s2 3->32, ky-split G=2: 1024 blocks
  conv_k<11,11,2,4, 3, 32,2,false,false,2,true ><<<1024, blk,0,stream>>>(x, k1, nullptr, P, 8,128,128,64,64);
  reduce_k<2, 32,true><<<1024, blk,0,stream>>>(P, b1, W0, 1048576);
  // conv1c 3x3 32->32 @64x64: 1024 blocks direct
  conv_k< 3, 3,1,1,32, 32,1,true ,true ,1,false><<<1024, blk,0,stream>>>(W0, k1c, b1c, W1, 8,64,64,64,64);
  // conv2 11x11 s2 32->64, ci-split G=4: 1024 blocks
  conv_k<11,11,2,4,32, 64,2,false,false,4,false><<<1024, blk,0,stream>>>(W1, k2, nullptr, P, 8,64,64,32,32);
  reduce_k<4, 64,true><<< 512, blk,0,stream>>>(P, b2, W0, 524288);
  // conv2c 3x3 64->64 @32x32, ci-split G=2: 1024 blocks
  conv_k< 3, 3,1,1,64, 64,1,false,false,2,false><<<1024, blk,0,stream>>>(W0, k2c, nullptr, P, 8,32,32,32,32);
  reduce_k<2, 64,true><<< 512, blk,0,stream>>>(P, b2c, W1, 524288);
  // conv3 11x11 s2 64->128, ci-split G=8: 1024 blocks
  conv_k<11,11,2,4,64,128,2,false,false,8,false><<<1024, blk,0,stream>>>(W1, k3, nullptr, P, 8,32,32,16,16);
  reduce_k<8,128,true><<< 256, blk,0,stream>>>(P, b3, W0, 262144);
  // conv3c 3x3 128->128 @16x16, ci-split G=4: 1024 blocks (partials -> vq)
  conv_k< 3, 3,1,1,128,128,1,false,false,4,false><<<1024, blk,0,stream>>>(W0, k3c, nullptr, P, 8,16,16,16,16);
  // ---- VQ: reduce 4 partials + b3c, argmin over 256 codes, gather ----
  vq_k<4><<<512, blk,0,stream>>>(P, b3c, cb, W1, 2048);
  // ---- decoder ----
  // tconv1 5x5 s2 128->64, ci-split G=4: 2048 blocks
  tconv_k<128,64,1,4,false><<<2048, blk,0,stream>>>(W1, tk1, nullptr, P, 8,16,16,32,32);
  reduce_k<4, 64,true><<< 512, blk,0,stream>>>(P, tb1, W0, 524288);
  // tk1c 3x3 64->64 @32x32, ci-split G=2: 1024 blocks
  conv_k< 3, 3,1,1,64, 64,1,false,false,2,false><<<1024, blk,0,stream>>>(W0, tk1c, nullptr, P, 8,32,32,32,32);
  reduce_k<2, 64,true><<< 512, blk,0,stream>>>(P, tb1c, W1, 524288);
  // tconv2 5x5 s2 64->32, ci-split G=2: 1024 blocks
  tconv_k< 64,32,2,2,false><<<1024, blk,0,stream>>>(W1, tk2, nullptr, P, 8,32,32,64,64);
  reduce_k<2, 32,true><<<1024, blk,0,stream>>>(P, tb2, W0, 1048576);
  // tk2c 3x3 32->32 @64x64: 1024 blocks direct
  conv_k< 3, 3,1,1,32, 32,1,true ,true ,1,false><<<1024, blk,0,stream>>>(W0, tk2c, tb2c, W1, 8,64,64,64,64);
  // tconv3 5x5 s2 32->32: 2048 blocks direct, out = P (16 MB)
  tconv_k< 32,32,2,1,true ><<<2048, blk,0,stream>>>(W1, tk3, tb3, P, 8,64,64,128,128);
  // conv_last 3x3 32->3, ky-split G=3: 1536 blocks, partials at S[0..1.18M)
  conv_last_k<<<1536, blk,0,stream>>>(P, tk3c, S, 8,128,128);
  reduce_last_k<<<384, blk,0,stream>>>(S, tb3c, out, 393216);
}

// Round 6
// 1169.810 us; speedup vs baseline: 2.7861x; 2.7861x over previous
//
#include <hip/hip_runtime.h>

#define DI __device__ __forceinline__
DI float silu_f(float x){ return x * (1.0f/(1.0f+__expf(-x))); }

// ---------------------------------------------------------------------------
// Direct conv, NHWC input, HWIO weights (round-2 proven template).
// Thread = NPIX pixels x 4 co. G>1: ci-split, group in LOW bits of blockIdx.
// Partials (BIAS=false) at out + g*total*COUT.
// NOTE: per-output fp32 fmaf chain order (ky->kx->ci->r) is independent of
// NPIX and grid size; encoder G-splits are LOCKED to round-2's passing
// config because the VQ argmin is sensitive to latent rounding.
// ---------------------------------------------------------------------------
template<int KH,int KW,int STRIDE,int PAD,int CIN,int COUT,int NPIX,
         bool ACT,bool BIAS,int G>
__global__ __launch_bounds__(256) void conv_k(
    const float* __restrict__ in, const float* __restrict__ w,
    const float* __restrict__ bias, float* __restrict__ out,
    int N,int H,int W,int OH,int OW)
{
  constexpr int COQ  = COUT/4;
  constexpr int CLEN = (G==1) ? CIN : CIN/G;
  constexpr int GSH  = (G==8)?3:(G==4)?2:(G==2)?1:0;
  static_assert(G==1||G==2||G==4||G==8, "G");
  static_assert(CLEN==3 || (CLEN%4)==0, "ci");

  const int g  = blockIdx.x & (G-1);
  const int bx = blockIdx.x >> GSH;
  const int total = N*OH*OW;
  if (G>1) out += (size_t)g * total * COUT;
  const int ci_off = (G>1) ? g*CLEN : 0;

  int idx = bx*256 + (int)threadIdx.x;
  int cq = idx % COQ;
  int pg = idx / COQ;
  int co = cq*4;
  int p0 = pg*NPIX;
  if (p0 >= total) return;

  float acc[NPIX][4] = {};
  int iy0[NPIX], ix0[NPIX]; const float* base[NPIX]; bool pv[NPIX];
#pragma unroll
  for (int t=0;t<NPIX;t++){
    int p=p0+t; pv[t]=(p<total); int pp=pv[t]?p:p0;
    int ox=pp%OW; int r=pp/OW; int oy=r%OH; int n=r/OH;
    iy0[t]=oy*STRIDE-PAD; ix0[t]=ox*STRIDE-PAD;
    base[t]=in+(size_t)n*H*W*CIN + ci_off;
  }

  for (int ky=0; ky<KH; ky++){
    for (int kx=0; kx<KW; kx++){
      const float* wp = w + ((size_t)(ky*KW+kx)*CIN + ci_off)*COUT + co;
      const float* ip[NPIX]; bool ok[NPIX];
#pragma unroll
      for (int t=0;t<NPIX;t++){
        int iy=iy0[t]+ky, ix=ix0[t]+kx;
        ok[t]=pv[t] && iy>=0 && iy<H && ix>=0 && ix<W;
        ip[t]=base[t]+(size_t)(iy*W+ix)*CIN;
      }
      if constexpr (CLEN==3){
        float wv[3][4];
        *(float4*)wv[0]=*(const float4*)(wp);
        *(float4*)wv[1]=*(const float4*)(wp+COUT);
        *(float4*)wv[2]=*(const float4*)(wp+2*COUT);
#pragma unroll
        for (int t=0;t<NPIX;t++){
          float v0=ok[t]?ip[t][0]:0.f;
          float v1=ok[t]?ip[t][1]:0.f;
          float v2=ok[t]?ip[t][2]:0.f;
#pragma unroll
          for (int j=0;j<4;j++)
            acc[t][j]=fmaf(v0,wv[0][j],fmaf(v1,wv[1][j],fmaf(v2,wv[2][j],acc[t][j])));
        }
      } else {
#pragma unroll 2
        for (int ci=0; ci<CLEN; ci+=4){
          float wv[4][4];
#pragma unroll
          for (int r=0;r<4;r++)
            *(float4*)wv[r] = *(const float4*)(wp + (ci+r)*COUT);
#pragma unroll
          for (int t=0;t<NPIX;t++){
            float va[4];
            *(float4*)va = ok[t] ? *(const float4*)(ip[t]+ci)
                                 : make_float4(0.f,0.f,0.f,0.f);
#pragma unroll
            for (int r=0;r<4;r++)
#pragma unroll
              for (int j=0;j<4;j++)
                acc[t][j]=fmaf(va[r],wv[r][j],acc[t][j]);
          }
        }
      }
    }
  }

  float bv[4]={0.f,0.f,0.f,0.f};
  if constexpr (BIAS) *(float4*)bv = *(const float4*)(bias+co);
#pragma unroll
  for (int t=0;t<NPIX;t++) if (pv[t]){
    float o[4];
#pragma unroll
    for (int j=0;j<4;j++){
      float v = acc[t][j]+bv[j];
      o[j] = ACT ? silu_f(v) : v;
    }
    *(float4*)(out + (size_t)(p0+t)*COUT + co) = *(float4*)o;
  }
}

// ---------------------------------------------------------------------------
// reduce G partials (stride n) + bias + optional silu.
// ---------------------------------------------------------------------------
template<int G,int COUT,bool ACT>
__global__ __launch_bounds__(256) void reduce_k(
    const float* __restrict__ p, const float* __restrict__ bias,
    float* __restrict__ out, int n)
{
  int i = (blockIdx.x*256+threadIdx.x)*4;
  if (i>=n) return;
  float a[4]; *(float4*)a = *(const float4*)(p+i);
#pragma unroll
  for (int g=1; g<G; g++){
    float b[4]; *(float4*)b = *(const float4*)(p+(size_t)g*n+i);
#pragma unroll
    for (int j=0;j<4;j++) a[j]+=b[j];
  }
  float bv[4]; *(float4*)bv = *(const float4*)(bias + (i % COUT));
#pragma unroll
  for (int j=0;j<4;j++){
    float v=a[j]+bv[j];
    a[j] = ACT ? silu_f(v) : v;
  }
  *(float4*)(out+i) = *(float4*)a;
}

// ---------------------------------------------------------------------------
// conv_transpose 5x5 stride 2 SAME (verified r0 mapping). parity = b&3,
// ci-group = (b>>2)&(G-1), spatial = b>>(2+GSH). DIRECT: bias+silu in-kernel.
// ---------------------------------------------------------------------------
template<int CIN,int COUT,int NPIX,int G,bool DIRECT>
__global__ __launch_bounds__(256) void tconv_k(
    const float* __restrict__ in, const float* __restrict__ w,
    const float* __restrict__ bias, float* __restrict__ out,
    int N,int H,int W,int OH,int OW)
{
  constexpr int COQ  = COUT/4;
  constexpr int CLEN = (G==1)?CIN:CIN/G;
  constexpr int GSH  = (G==8)?3:(G==4)?2:(G==2)?1:0;
  const int par = blockIdx.x & 3;
  const int py = par>>1, px = par&1;
  const int g  = (blockIdx.x>>2) & (G-1);
  const int bx = blockIdx.x >> (2+GSH);
  const int NKY = py?3:2, NKX = px?3:2;
  const int OHh=OH>>1, OWh=OW>>1;
  const int total = N*OHh*OWh;
  if (G>1) out += (size_t)g * N*OH*OW*COUT;

  int idx = bx*256 + (int)threadIdx.x;
  int cq = idx % COQ;
  int pg = idx / COQ;
  int co = cq*4;
  int p0 = pg*NPIX;
  if (p0 >= total) return;

  float acc[NPIX][4] = {};
  int yy[NPIX], xx[NPIX], nn[NPIX]; const float* base[NPIX]; bool pv[NPIX];
#pragma unroll
  for (int t=0;t<NPIX;t++){
    int p=p0+t; pv[t]=(p<total); int pp=pv[t]?p:p0;
    xx[t]=pp%OWh; int r=pp/OWh; yy[t]=r%OHh; nn[t]=r/OHh;
    base[t]=in+(size_t)nn[t]*H*W*CIN + g*CLEN;
  }

  for (int j=0;j<NKY;j++){
    int ky = 2*j + (py?0:1);
    for (int i=0;i<NKX;i++){
      int kx = 2*i + (px?0:1);
      const float* wp = w + ((size_t)(ky*5+kx)*CIN + g*CLEN)*COUT + co;
      const float* ip[NPIX]; bool ok[NPIX];
#pragma unroll
      for (int t=0;t<NPIX;t++){
        int iy=yy[t]+j-1, ix=xx[t]+i-1;
        ok[t]=pv[t] && iy>=0 && iy<H && ix>=0 && ix<W;
        ip[t]=base[t]+(size_t)(iy*W+ix)*CIN;
      }
#pragma unroll 2
      for (int ci=0; ci<CLEN; ci+=4){
        float wv[4][4];
#pragma unroll
        for (int r=0;r<4;r++)
          *(float4*)wv[r] = *(const float4*)(wp + (ci+r)*COUT);
#pragma unroll
        for (int t=0;t<NPIX;t++){
          float va[4];
          *(float4*)va = ok[t] ? *(const float4*)(ip[t]+ci)
                               : make_float4(0.f,0.f,0.f,0.f);
#pragma unroll
          for (int r=0;r<4;r++)
#pragma unroll
            for (int jj=0;jj<4;jj++)
              acc[t][jj]=fmaf(va[r],wv[r][jj],acc[t][jj]);
        }
      }
    }
  }

  float bv[4]={0.f,0.f,0.f,0.f};
  if constexpr (DIRECT) *(float4*)bv = *(const float4*)(bias+co);
#pragma unroll
  for (int t=0;t<NPIX;t++) if (pv[t]){
    float o[4];
#pragma unroll
    for (int jj=0;jj<4;jj++){
      float v = acc[t][jj]+bv[jj];
      o[jj] = DIRECT ? silu_f(v) : v;
    }
    *(float4*)(out + (((size_t)nn[t]*OH + (2*yy[t]+py))*OW + (2*xx[t]+px))*COUT + co) = *(float4*)o;
  }
}

// ---------------------------------------------------------------------------
// VQ fused with conv3c 2-partial reduction + bias (round-2 EXACT version;
// the argmin is rounding-sensitive, do not change accumulation order).
// ---------------------------------------------------------------------------
__global__ __launch_bounds__(256) void vq_k(
    const float* __restrict__ p, const float* __restrict__ bias,
    const float* __restrict__ cb, float* __restrict__ q, int NLat)
{
  __shared__ float slat[4][128];
  int wave = threadIdx.x >> 6;
  int lane = threadIdx.x & 63;
  int l = blockIdx.x*4 + wave;
  if (l >= NLat) return;
  const float* p0 = p + (size_t)l*128;
  const float* p1 = p0 + (size_t)NLat*128;
  slat[wave][lane]    = p0[lane]    + p1[lane]    + bias[lane];
  slat[wave][lane+64] = p0[lane+64] + p1[lane+64] + bias[lane+64];

  float bestd = INFINITY; int besti = 0;
  for (int c0=0;c0<256;c0+=64){
    int c = c0 + lane;
    const float* cp = cb + (size_t)c*128;
    float d = 0.f;
#pragma unroll 8
    for (int k=0;k<128;k+=4){
      float4 cv = *reinterpret_cast<const float4*>(cp+k);
      float d0 = slat[wave][k+0]-cv.x;
      float d1 = slat[wave][k+1]-cv.y;
      float d2 = slat[wave][k+2]-cv.z;
      float d3 = slat[wave][k+3]-cv.w;
      d += d0*d0; d += d1*d1; d += d2*d2; d += d3*d3;
    }
    if (d < bestd) { bestd = d; besti = c; }
  }
  for (int off=32; off; off>>=1){
    float od = __shfl_down(bestd, off);
    int   oi = __shfl_down(besti, off);
    if (od < bestd || (od == bestd && oi < besti)) { bestd=od; besti=oi; }
  }
  besti = __shfl(besti, 0);
  const float* cp = cb + (size_t)besti*128;
  float* qp = q + (size_t)l*128;
  qp[lane]    = cp[lane];
  qp[lane+64] = cp[lane+64];
}

// ---------------------------------------------------------------------------
// Final 3x3 conv 32->3 split over ky rows (g = blockIdx%3). Writes partials.
// ---------------------------------------------------------------------------
__global__ __launch_bounds__(256) void conv_last_k(
    const float* __restrict__ in, const float* __restrict__ w,
    float* __restrict__ p, int N,int H,int W)
{
  int g = blockIdx.x % 3;
  int bx = blockIdx.x / 3;
  int pix = bx*256 + threadIdx.x;
  int total = N*H*W;
  if (pix>=total) return;
  int x = pix % W; int r = pix / W; int y = r % H; int n = r / H;
  float a0=0.f, a1=0.f, a2=0.f;
  int iy = y + g - 1;
  if (iy>=0 && iy<H){
    const float* base = in + ((size_t)n*H + iy)*W*32;
    for (int kx=0;kx<3;kx++){
      int ix=x+kx-1; if(ix<0||ix>=W) continue;
      const float* ip = base + (size_t)ix*32;
      const float* wp = w + (size_t)((g*3+kx)*32)*3;
#pragma unroll
      for (int ci=0;ci<32;ci+=4){
        float va[4]; *(float4*)va = *(const float4*)(ip+ci);
        float wv[12];
        *(float4*)(wv+0) = *(const float4*)(wp+ci*3+0);
        *(float4*)(wv+4) = *(const float4*)(wp+ci*3+4);
        *(float4*)(wv+8) = *(const float4*)(wp+ci*3+8);
#pragma unroll
        for (int r2=0;r2<4;r2++){
          a0 = fmaf(va[r2], wv[r2*3+0], a0);
          a1 = fmaf(va[r2], wv[r2*3+1], a1);
          a2 = fmaf(va[r2], wv[r2*3+2], a2);
        }
      }
    }
  }
  float* pp = p + (size_t)g*total*3 + (size_t)pix*3;
  pp[0]=a0; pp[1]=a1; pp[2]=a2;
}

__global__ __launch_bounds__(256) void reduce_last_k(
    const float* __restrict__ p, const float* __restrict__ bias,
    float* __restrict__ out, int n)
{
  int i = (blockIdx.x*256+threadIdx.x)*4;
  if (i>=n) return;
  float a[4]; *(float4*)a = *(const float4*)(p+i);
#pragma unroll
  for (int g=1; g<3; g++){
    float b[4]; *(float4*)b = *(const float4*)(p+(size_t)g*n+i);
#pragma unroll
    for (int j=0;j<4;j++) a[j]+=b[j];
  }
  float o[4];
#pragma unroll
  for (int j=0;j<4;j++) o[j] = a[j] + bias[(i+j)%3];
  *(float4*)(out+i) = *(float4*)o;
}

extern "C" void kernel_launch(void* const* d_in, const int* in_sizes, int n_in,
                              void* d_out, int out_size, void* d_ws, size_t ws_size,
                              hipStream_t stream) {
  const float* x    = (const float*)d_in[0];
  const float* k1   = (const float*)d_in[1];  const float* b1  = (const float*)d_in[2];
  const float* k1c  = (const float*)d_in[3];  const float* b1c = (const float*)d_in[4];
  const float* k2   = (const float*)d_in[5];  const float* b2  = (const float*)d_in[6];
  const float* k2c  = (const float*)d_in[7];  const float* b2c = (const float*)d_in[8];
  const float* k3   = (const float*)d_in[9];  const float* b3  = (const float*)d_in[10];
  const float* k3c  = (const float*)d_in[11]; const float* b3c = (const float*)d_in[12];
  const float* cb   = (const float*)d_in[13];
  const float* tk1  = (const float*)d_in[14]; const float* tb1  = (const float*)d_in[15];
  const float* tk1c = (const float*)d_in[16]; const float* tb1c = (const float*)d_in[17];
  const float* tk2  = (const float*)d_in[18]; const float* tb2  = (const float*)d_in[19];
  const float* tk2c = (const float*)d_in[20]; const float* tb2c = (const float*)d_in[21];
  const float* tk3  = (const float*)d_in[22]; const float* tb3  = (const float*)d_in[23];
  const float* tk3c = (const float*)d_in[24]; const float* tb3c = (const float*)d_in[25];
  float* out = (float*)d_out;

  float* S  = (float*)d_ws;
  float* W0 = S;                 // [0 .. 1M) floats
  float* W1 = S + 1048576;       // [1M .. 2M)
  float* P  = S + 2097152;       // [2M .. 6M)  partials / big activation
  // total ws: 6M floats = 24 MB

  dim3 blk(256);
  // ---- encoder: G-splits LOCKED to round-2 passing config (VQ argmin) ----
  // conv1 11x11 s2 3->32: G=1 direct, NPIX=1 -> 1024 blocks
  conv_k<11,11,2,4,  3, 32,1,true ,true ,1><<<1024,blk,0,stream>>>(x,  k1,  b1,  W0, 8,128,128,64,64);
  // conv1c 3x3 32->32 @64x64: G=1 direct, NPIX=1 -> 1024 blocks
  conv_k< 3, 3,1,1, 32, 32,1,true ,true ,1><<<1024,blk,0,stream>>>(W0, k1c, b1c, W1, 8,64,64,64,64);
  // conv2 11x11 s2 32->64: G=2 (r2 config), NPIX=1 -> 1024 blocks
  conv_k<11,11,2,4, 32, 64,1,false,false,2><<<1024,blk,0,stream>>>(W1, k2,  nullptr, P, 8,64,64,32,32);
  reduce_k<2, 64,true><<< 512,blk,0,stream>>>(P, b2,  W0, 524288);
  // conv2c 3x3 64->64 @32x32: G=1 direct (r2 config), NPIX=1 -> 512 blocks
  conv_k< 3, 3,1,1, 64, 64,1,true ,true ,1><<< 512,blk,0,stream>>>(W0, k2c, b2c, W1, 8,32,32,32,32);
  // conv3 11x11 s2 64->128: G=4 (r2 config), NPIX=1 -> 1024 blocks
  conv_k<11,11,2,4, 64,128,1,false,false,4><<<1024,blk,0,stream>>>(W1, k3,  nullptr, P, 8,32,32,16,16);
  reduce_k<4,128,true><<< 256,blk,0,stream>>>(P, b3,  W0, 262144);
  // conv3c 3x3 128->128 @16x16: G=2 (r2 config), NPIX=1 -> 512 blocks
  conv_k< 3, 3,1,1,128,128,1,false,false,2><<< 512,blk,0,stream>>>(W0, k3c, nullptr, P, 8,16,16,16,16);
  // ---- VQ: r2-exact 2-partial reduce + argmin + gather ----
  vq_k<<<512,blk,0,stream>>>(P, b3c, cb, W1, 2048);
  // ---- decoder (post-argmin; rounding-insensitive, r3-proven configs) ----
  // tconv1 5x5 s2 128->64: G=4, NPIX=1 -> 2048 blocks
  tconv_k<128,64,1,4,false><<<2048,blk,0,stream>>>(W1, tk1, nullptr, P, 8,16,16,32,32);
  reduce_k<4, 64,true><<< 512,blk,0,stream>>>(P, tb1,  W0, 524288);
  // tk1c 3x3 64->64 @32x32: G=2, NPIX=1 -> 1024 blocks
  conv_k< 3, 3,1,1, 64, 64,1,false,false,2><<<1024,blk,0,stream>>>(W0, tk1c, nullptr, P, 8,32,32,32,32);
  reduce_k<2, 64,true><<< 512,blk,0,stream>>>(P, tb1c, W1, 524288);
  // tconv2 5x5 s2 64->32: G=2, NPIX=2 -> 1024 blocks
  tconv_k< 64,32,2,2,false><<<1024,blk,0,stream>>>(W1, tk2, nullptr, P, 8,32,32,64,64);
  reduce_k<2, 32,true><<<1024,blk,0,stream>>>(P, tb2,  W0, 1048576);
  // tk2c 3x3 32->32 @64x64: G=1 direct, NPIX=1 -> 1024 blocks
  conv_k< 3, 3,1,1, 32, 32,1,true ,true ,1><<<1024,blk,0,stream>>>(W0, tk2c, tb2c, W1, 8,64,64,64,64);
  // tconv3 5x5 s2 32->32: G=1 direct, NPIX=2 -> 2048 blocks
  tconv_k< 32,32,2,1,true ><<<2048,blk,0,stream>>>(W1, tk3, tb3, P, 8,64,64,128,128);
  // conv_last 3x3 32->3: ky-split g=b%3, 1536 blocks + reduce
  conv_last_k<<<1536,blk,0,stream>>>(P, tk3c, S, 8,128,128);
  reduce_last_k<<<384,blk,0,stream>>>(S, tb3c, out, 393216);
}

// Round 7
// 705.451 us; speedup vs baseline: 4.6200x; 1.6582x over previous
//
#include <hip/hip_runtime.h>

#define DI __device__ __forceinline__
DI float silu_f(float x){ return x * (1.0f/(1.0f+__expf(-x))); }

template<int X> struct LOG2 { static constexpr int v = 1 + LOG2<X/2>::v; };
template<> struct LOG2<1> { static constexpr int v = 0; };

// ---------------------------------------------------------------------------
// Direct conv, NHWC in, HWIO weights, LDS-staged weight slices.
// Thread = NPIX pixels x 4 co. G: ci-split (FROZEN per layer at round-2/6
// values — VQ argmin is sensitive to latent rounding; G changes accumulation
// order). CS: co-split across blocks (NEW, numerics-free: each output's fmaf
// chain ky->kx->ci->r is unchanged; only thread->output mapping changes).
// Stage-all if filter slice <= 47KB else per-ky-row. Grids EXACT (no early
// return; barriers uniform). LDS staging mechanism exonerated by r4/r5
// bit-identical failures (failure was encoder G-splits, not staging).
// ---------------------------------------------------------------------------
template<int KH,int KW,int STRIDE,int PAD,int CIN,int COUT,int NPIX,
         bool ACT,bool BIAS,int G,int CS>
__global__ __launch_bounds__(256) void conv_k(
    const float* __restrict__ in, const float* __restrict__ w,
    const float* __restrict__ bias, float* __restrict__ out,
    int N,int H,int W,int OH,int OW)
{
  constexpr int CLEN = CIN/G;
  constexpr int COB  = COUT/CS;
  constexpr int COQ  = COB/4;
  constexpr int GSH  = LOG2<G>::v;
  constexpr int CSH  = LOG2<CS>::v;
  constexpr int TAPF = CLEN*COB;                 // floats per staged tap
  constexpr bool SALL = (KH*KW*TAPF*4) <= 47*1024;
  constexpr int NTAP = SALL ? KH*KW : KW;
  static_assert(CLEN==3 || (CLEN%4)==0, "ci");
  __shared__ float sw[NTAP*TAPF];

  const int g  = blockIdx.x & (G-1);
  const int cs = (blockIdx.x >> GSH) & (CS-1);
  const int bx = blockIdx.x >> (GSH+CSH);
  const int total = N*OH*OW;
  if (G>1) out += (size_t)g * total * COUT;
  const int ci_off  = g*CLEN;
  const int co_base = cs*COB;

  int idx = bx*256 + (int)threadIdx.x;
  int cq = idx % COQ;
  int pg = idx / COQ;
  int co = cq*4;                 // within block's co slice
  int gco = co_base + co;        // global co
  int p0 = pg*NPIX;

  float acc[NPIX][4] = {};
  int iy0[NPIX], ix0[NPIX]; const float* base[NPIX]; bool pv[NPIX];
#pragma unroll
  for (int t=0;t<NPIX;t++){
    int p=p0+t; pv[t]=(p<total); int pp=pv[t]?p:0;
    int ox=pp%OW; int r=pp/OW; int oy=r%OH; int n=r/OH;
    iy0[t]=oy*STRIDE-PAD; ix0[t]=ox*STRIDE-PAD;
    base[t]=in+(size_t)n*H*W*CIN + ci_off;
  }

  auto stage = [&](int tap0){
    constexpr int TQ = TAPF/4;
    constexpr int V  = NTAP*TQ;
    for (int v=threadIdx.x; v<V; v+=256){
      int tap = v / TQ; int rem = v - tap*TQ;
      float4 q;
      if constexpr (CS==1){
        // tap block is CLEN*COUT contiguous (ci rows adjacent in HWIO)
        const float4* src = (const float4*)(w + ((size_t)(tap0+tap)*CIN + ci_off)*COUT);
        q = src[rem];
      } else {
        int ci = rem / (COB/4); int r2 = rem - ci*(COB/4);
        q = *(const float4*)(w + ((size_t)(tap0+tap)*CIN + ci_off + ci)*COUT
                               + co_base + r2*4);
      }
      *(float4*)(sw + (size_t)tap*TAPF + rem*4) = q;
    }
  };

  if constexpr (SALL){
    stage(0);
    __syncthreads();
  }

  for (int ky=0; ky<KH; ky++){
    if constexpr (!SALL){
      __syncthreads();
      stage(ky*KW);
      __syncthreads();
    }
    const float* swr = SALL ? sw + (size_t)ky*KW*TAPF : sw;
    for (int kx=0; kx<KW; kx++){
      const float* swt = swr + (size_t)kx*TAPF;
      const float* ip[NPIX]; bool ok[NPIX];
#pragma unroll
      for (int t=0;t<NPIX;t++){
        int iy=iy0[t]+ky, ix=ix0[t]+kx;
        ok[t]=pv[t] && iy>=0 && iy<H && ix>=0 && ix<W;
        ip[t]=base[t]+(size_t)(iy*W+ix)*CIN;
      }
      if constexpr (CLEN==3){
        float wv[3][4];
        *(float4*)wv[0]=*(const float4*)(swt + 0*COB + co);
        *(float4*)wv[1]=*(const float4*)(swt + 1*COB + co);
        *(float4*)wv[2]=*(const float4*)(swt + 2*COB + co);
#pragma unroll
        for (int t=0;t<NPIX;t++){
          float v0=ok[t]?ip[t][0]:0.f;
          float v1=ok[t]?ip[t][1]:0.f;
          float v2=ok[t]?ip[t][2]:0.f;
#pragma unroll
          for (int j=0;j<4;j++)
            acc[t][j]=fmaf(v0,wv[0][j],fmaf(v1,wv[1][j],fmaf(v2,wv[2][j],acc[t][j])));
        }
      } else {
#pragma unroll 2
        for (int ci=0; ci<CLEN; ci+=4){
          float wv[4][4];
#pragma unroll
          for (int r=0;r<4;r++)
            *(float4*)wv[r] = *(const float4*)(swt + (ci+r)*COB + co);
#pragma unroll
          for (int t=0;t<NPIX;t++){
            float va[4];
            *(float4*)va = ok[t] ? *(const float4*)(ip[t]+ci)
                                 : make_float4(0.f,0.f,0.f,0.f);
#pragma unroll
            for (int r=0;r<4;r++)
#pragma unroll
              for (int j=0;j<4;j++)
                acc[t][j]=fmaf(va[r],wv[r][j],acc[t][j]);
          }
        }
      }
    }
  }

  float bv[4]={0.f,0.f,0.f,0.f};
  if constexpr (BIAS) *(float4*)bv = *(const float4*)(bias+gco);
#pragma unroll
  for (int t=0;t<NPIX;t++) if (pv[t]){
    float o[4];
#pragma unroll
    for (int j=0;j<4;j++){
      float v = acc[t][j]+bv[j];
      o[j] = ACT ? silu_f(v) : v;
    }
    *(float4*)(out + (size_t)(p0+t)*COUT + gco) = *(float4*)o;
  }
}

// ---------------------------------------------------------------------------
// reduce G partials (stride n) + bias + optional silu.
// ---------------------------------------------------------------------------
template<int G,int COUT,bool ACT>
__global__ __launch_bounds__(256) void reduce_k(
    const float* __restrict__ p, const float* __restrict__ bias,
    float* __restrict__ out, int n)
{
  int i = (blockIdx.x*256+threadIdx.x)*4;
  if (i>=n) return;
  float a[4]; *(float4*)a = *(const float4*)(p+i);
#pragma unroll
  for (int g=1; g<G; g++){
    float b[4]; *(float4*)b = *(const float4*)(p+(size_t)g*n+i);
#pragma unroll
    for (int j=0;j<4;j++) a[j]+=b[j];
  }
  float bv[4]; *(float4*)bv = *(const float4*)(bias + (i % COUT));
#pragma unroll
  for (int j=0;j<4;j++){
    float v=a[j]+bv[j];
    a[j] = ACT ? silu_f(v) : v;
  }
  *(float4*)(out+i) = *(float4*)a;
}

// ---------------------------------------------------------------------------
// conv_transpose 5x5 s2 SAME (verified r0 mapping), per-tap LDS weight stage.
// parity = b&3, ci-group = (b>>2)&(G-1), spatial = b>>(2+GSH). No early
// return (barriers). DIRECT: bias+silu in-kernel.
// ---------------------------------------------------------------------------
template<int CIN,int COUT,int NPIX,int G,bool DIRECT>
__global__ __launch_bounds__(256) void tconv_k(
    const float* __restrict__ in, const float* __restrict__ w,
    const float* __restrict__ bias, float* __restrict__ out,
    int N,int H,int W,int OH,int OW)
{
  constexpr int COQ  = COUT/4;
  constexpr int CLEN = CIN/G;
  constexpr int GSH  = LOG2<G>::v;
  constexpr int TAPF = CLEN*COUT;
  __shared__ float sw[TAPF];
  const int par = blockIdx.x & 3;
  const int py = par>>1, px = par&1;
  const int g  = (blockIdx.x>>2) & (G-1);
  const int bx = blockIdx.x >> (2+GSH);
  const int NKY = py?3:2, NKX = px?3:2;
  const int OHh=OH>>1, OWh=OW>>1;
  const int total = N*OHh*OWh;
  if (G>1) out += (size_t)g * N*OH*OW*COUT;

  int idx = bx*256 + (int)threadIdx.x;
  int cq = idx % COQ;
  int pg = idx / COQ;
  int co = cq*4;
  int p0 = pg*NPIX;

  float acc[NPIX][4] = {};
  int yy[NPIX], xx[NPIX], nn[NPIX]; const float* base[NPIX]; bool pv[NPIX];
#pragma unroll
  for (int t=0;t<NPIX;t++){
    int p=p0+t; pv[t]=(p<total); int pp=pv[t]?p:0;
    xx[t]=pp%OWh; int r=pp/OWh; yy[t]=r%OHh; nn[t]=r/OHh;
    base[t]=in+(size_t)nn[t]*H*W*CIN + g*CLEN;
  }

  for (int j=0;j<NKY;j++){
    int ky = 2*j + (py?0:1);
    for (int i=0;i<NKX;i++){
      int kx = 2*i + (px?0:1);
      __syncthreads();
      {
        constexpr int V = TAPF/4;
        const float4* src = (const float4*)(w + ((size_t)(ky*5+kx)*CIN + g*CLEN)*COUT);
        for (int v=threadIdx.x; v<V; v+=256) ((float4*)sw)[v]=src[v];
      }
      __syncthreads();
      const float* ip[NPIX]; bool ok[NPIX];
#pragma unroll
      for (int t=0;t<NPIX;t++){
        int iy=yy[t]+j-1, ix=xx[t]+i-1;
        ok[t]=pv[t] && iy>=0 && iy<H && ix>=0 && ix<W;
        ip[t]=base[t]+(size_t)(iy*W+ix)*CIN;
      }
#pragma unroll 2
      for (int ci=0; ci<CLEN; ci+=4){
        float wv[4][4];
#pragma unroll
        for (int r=0;r<4;r++)
          *(float4*)wv[r] = *(const float4*)(sw + (ci+r)*COUT + co);
#pragma unroll
        for (int t=0;t<NPIX;t++){
          float va[4];
          *(float4*)va = ok[t] ? *(const float4*)(ip[t]+ci)
                               : make_float4(0.f,0.f,0.f,0.f);
#pragma unroll
          for (int r=0;r<4;r++)
#pragma unroll
            for (int jj=0;jj<4;jj++)
              acc[t][jj]=fmaf(va[r],wv[r][jj],acc[t][jj]);
        }
      }
    }
  }

  float bv[4]={0.f,0.f,0.f,0.f};
  if constexpr (DIRECT) *(float4*)bv = *(const float4*)(bias+co);
#pragma unroll
  for (int t=0;t<NPIX;t++) if (pv[t]){
    float o[4];
#pragma unroll
    for (int jj=0;jj<4;jj++){
      float v = acc[t][jj]+bv[jj];
      o[jj] = DIRECT ? silu_f(v) : v;
    }
    *(float4*)(out + (((size_t)nn[t]*OH + (2*yy[t]+py))*OW + (2*xx[t]+px))*COUT + co) = *(float4*)o;
  }
}

// ---------------------------------------------------------------------------
// VQ fused with conv3c 2-partial reduction + bias (round-2 EXACT — FROZEN).
// ---------------------------------------------------------------------------
__global__ __launch_bounds__(256) void vq_k(
    const float* __restrict__ p, const float* __restrict__ bias,
    const float* __restrict__ cb, float* __restrict__ q, int NLat)
{
  __shared__ float slat[4][128];
  int wave = threadIdx.x >> 6;
  int lane = threadIdx.x & 63;
  int l = blockIdx.x*4 + wave;
  if (l >= NLat) return;
  const float* p0 = p + (size_t)l*128;
  const float* p1 = p0 + (size_t)NLat*128;
  slat[wave][lane]    = p0[lane]    + p1[lane]    + bias[lane];
  slat[wave][lane+64] = p0[lane+64] + p1[lane+64] + bias[lane+64];

  float bestd = INFINITY; int besti = 0;
  for (int c0=0;c0<256;c0+=64){
    int c = c0 + lane;
    const float* cp = cb + (size_t)c*128;
    float d = 0.f;
#pragma unroll 8
    for (int k=0;k<128;k+=4){
      float4 cv = *reinterpret_cast<const float4*>(cp+k);
      float d0 = slat[wave][k+0]-cv.x;
      float d1 = slat[wave][k+1]-cv.y;
      float d2 = slat[wave][k+2]-cv.z;
      float d3 = slat[wave][k+3]-cv.w;
      d += d0*d0; d += d1*d1; d += d2*d2; d += d3*d3;
    }
    if (d < bestd) { bestd = d; besti = c; }
  }
  for (int off=32; off; off>>=1){
    float od = __shfl_down(bestd, off);
    int   oi = __shfl_down(besti, off);
    if (od < bestd || (od == bestd && oi < besti)) { bestd=od; besti=oi; }
  }
  besti = __shfl(besti, 0);
  const float* cp = cb + (size_t)besti*128;
  float* qp = q + (size_t)l*128;
  qp[lane]    = cp[lane];
  qp[lane+64] = cp[lane+64];
}

// ---------------------------------------------------------------------------
// Final 3x3 conv 32->3 split over ky rows (g = blockIdx%3). Writes partials.
// ---------------------------------------------------------------------------
__global__ __launch_bounds__(256) void conv_last_k(
    const float* __restrict__ in, const float* __restrict__ w,
    float* __restrict__ p, int N,int H,int W)
{
  int g = blockIdx.x % 3;
  int bx = blockIdx.x / 3;
  int pix = bx*256 + threadIdx.x;
  int total = N*H*W;
  if (pix>=total) return;
  int x = pix % W; int r = pix / W; int y = r % H; int n = r / H;
  float a0=0.f, a1=0.f, a2=0.f;
  int iy = y + g - 1;
  if (iy>=0 && iy<H){
    const float* base = in + ((size_t)n*H + iy)*W*32;
    for (int kx=0;kx<3;kx++){
      int ix=x+kx-1; if(ix<0||ix>=W) continue;
      const float* ip = base + (size_t)ix*32;
      const float* wp = w + (size_t)((g*3+kx)*32)*3;
#pragma unroll
      for (int ci=0;ci<32;ci+=4){
        float va[4]; *(float4*)va = *(const float4*)(ip+ci);
        float wv[12];
        *(float4*)(wv+0) = *(const float4*)(wp+ci*3+0);
        *(float4*)(wv+4) = *(const float4*)(wp+ci*3+4);
        *(float4*)(wv+8) = *(const float4*)(wp+ci*3+8);
#pragma unroll
        for (int r2=0;r2<4;r2++){
          a0 = fmaf(va[r2], wv[r2*3+0], a0);
          a1 = fmaf(va[r2], wv[r2*3+1], a1);
          a2 = fmaf(va[r2], wv[r2*3+2], a2);
        }
      }
    }
  }
  float* pp = p + (size_t)g*total*3 + (size_t)pix*3;
  pp[0]=a0; pp[1]=a1; pp[2]=a2;
}

__global__ __launch_bounds__(256) void reduce_last_k(
    const float* __restrict__ p, const float* __restrict__ bias,
    float* __restrict__ out, int n)
{
  int i = (blockIdx.x*256+threadIdx.x)*4;
  if (i>=n) return;
  float a[4]; *(float4*)a = *(const float4*)(p+i);
#pragma unroll
  for (int g=1; g<3; g++){
    float b[4]; *(float4*)b = *(const float4*)(p+(size_t)g*n+i);
#pragma unroll
    for (int j=0;j<4;j++) a[j]+=b[j];
  }
  float o[4];
#pragma unroll
  for (int j=0;j<4;j++) o[j] = a[j] + bias[(i+j)%3];
  *(float4*)(out+i) = *(float4*)o;
}

extern "C" void kernel_launch(void* const* d_in, const int* in_sizes, int n_in,
                              void* d_out, int out_size, void* d_ws, size_t ws_size,
                              hipStream_t stream) {
  const float* x    = (const float*)d_in[0];
  const float* k1   = (const float*)d_in[1];  const float* b1  = (const float*)d_in[2];
  const float* k1c  = (const float*)d_in[3];  const float* b1c = (const float*)d_in[4];
  const float* k2   = (const float*)d_in[5];  const float* b2  = (const float*)d_in[6];
  const float* k2c  = (const float*)d_in[7];  const float* b2c = (const float*)d_in[8];
  const float* k3   = (const float*)d_in[9];  const float* b3  = (const float*)d_in[10];
  const float* k3c  = (const float*)d_in[11]; const float* b3c = (const float*)d_in[12];
  const float* cb   = (const float*)d_in[13];
  const float* tk1  = (const float*)d_in[14]; const float* tb1  = (const float*)d_in[15];
  const float* tk1c = (const float*)d_in[16]; const float* tb1c = (const float*)d_in[17];
  const float* tk2  = (const float*)d_in[18]; const float* tb2  = (const float*)d_in[19];
  const float* tk2c = (const float*)d_in[20]; const float* tb2c = (const float*)d_in[21];
  const float* tk3  = (const float*)d_in[22]; const float* tb3  = (const float*)d_in[23];
  const float* tk3c = (const float*)d_in[24]; const float* tb3c = (const float*)d_in[25];
  float* out = (float*)d_out;

  float* S  = (float*)d_ws;
  float* W0 = S;                 // [0 .. 1M) floats
  float* W1 = S + 1048576;       // [1M .. 2M)
  float* P  = S + 2097152;       // [2M .. 6M)
  dim3 blk(256);

  // ---- encoder: G-splits + fmaf order FROZEN to r6 (VQ argmin safety) ----
  // conv1 11x11 s2 3->32: G1 CS1, stage-all 46.5KB, NPIX=2 -> 512 blocks
  conv_k<11,11,2,4,  3, 32,2,true ,true ,1,1><<< 512,blk,0,stream>>>(x,  k1,  b1,  W0, 8,128,128,64,64);
  // conv1c 3x3 32->32 @64x64: G1 CS1, stage-all 36KB, NPIX=2 -> 512 blocks
  conv_k< 3, 3,1,1, 32, 32,2,true ,true ,1,1><<< 512,blk,0,stream>>>(W0, k1c, b1c, W1, 8,64,64,64,64);
  // conv2 11x11 s2 32->64: G2 CS1, per-ky 44KB, NPIX=2 -> 512 blocks
  conv_k<11,11,2,4, 32, 64,2,false,false,2,1><<< 512,blk,0,stream>>>(W1, k2,  nullptr, P, 8,64,64,32,32);
  reduce_k<2, 64,true><<< 512,blk,0,stream>>>(P, b2,  W0, 524288);
  // conv2c 3x3 64->64 @32x32: G1 CS1 direct, per-ky 48KB, NPIX=1 -> 512 blocks
  conv_k< 3, 3,1,1, 64, 64,1,true ,true ,1,1><<< 512,blk,0,stream>>>(W0, k2c, b2c, W1, 8,32,32,32,32);
  // conv3 11x11 s2 64->128: G4 CS2, per-ky 44KB, NPIX=2 -> 512 blocks
  conv_k<11,11,2,4, 64,128,2,false,false,4,2><<< 512,blk,0,stream>>>(W1, k3,  nullptr, P, 8,32,32,16,16);
  reduce_k<4,128,true><<< 256,blk,0,stream>>>(P, b3,  W0, 262144);
  // conv3c 3x3 128->128 @16x16: G2 CS2, per-ky 48KB, NPIX=1 -> 512 blocks
  conv_k< 3, 3,1,1,128,128,1,false,false,2,2><<< 512,blk,0,stream>>>(W0, k3c, nullptr, P, 8,16,16,16,16);
  // ---- VQ: r2-exact 2-partial reduce + argmin + gather (FROZEN) ----
  vq_k<<<512,blk,0,stream>>>(P, b3c, cb, W1, 2048);
  // ---- decoder (G frozen to r6; staging/NPIX numerics-free) ----
  // tconv1 5x5 s2 128->64: G4, per-tap 8KB, NPIX=2 -> 1024 blocks
  tconv_k<128,64,2,4,false><<<1024,blk,0,stream>>>(W1, tk1, nullptr, P, 8,16,16,32,32);
  reduce_k<4, 64,true><<< 512,blk,0,stream>>>(P, tb1,  W0, 524288);
  // tk1c 3x3 64->64 @32x32: G2 CS1, per-ky 24KB, NPIX=1 -> 1024 blocks
  conv_k< 3, 3,1,1, 64, 64,1,false,false,2,1><<<1024,blk,0,stream>>>(W0, tk1c, nullptr, P, 8,32,32,32,32);
  reduce_k<2, 64,true><<< 512,blk,0,stream>>>(P, tb1c, W1, 524288);
  // tconv2 5x5 s2 64->32: G2, per-tap 4KB, NPIX=2 -> 1024 blocks
  tconv_k< 64,32,2,2,false><<<1024,blk,0,stream>>>(W1, tk2, nullptr, P, 8,32,32,64,64);
  reduce_k<2, 32,true><<<1024,blk,0,stream>>>(P, tb2,  W0, 1048576);
  // tk2c 3x3 32->32 @64x64: G1 CS1, stage-all 36KB, NPIX=2 -> 512 blocks
  conv_k< 3, 3,1,1, 32, 32,2,true ,true ,1,1><<< 512,blk,0,stream>>>(W0, tk2c, tb2c, W1, 8,64,64,64,64);
  // tconv3 5x5 s2 32->32: G1 direct, per-tap 4KB, NPIX=2 -> 2048 blocks
  tconv_k< 32,32,2,1,true ><<<2048,blk,0,stream>>>(W1, tk3, tb3, P, 8,64,64,128,128);
  // conv_last 3x3 32->3: ky-split g=b%3, 1536 blocks + reduce
  conv_last_k<<<1536,blk,0,stream>>>(P, tk3c, S, 8,128,128);
  reduce_last_k<<<384,blk,0,stream>>>(S, tb3c, out, 393216);
}

// Round 8
// 572.540 us; speedup vs baseline: 5.6925x; 1.2321x over previous
//
#include <hip/hip_runtime.h>

#define DI __device__ __forceinline__
DI float silu_f(float x){ return x * (1.0f/(1.0f+__expf(-x))); }

template<int X> struct LOG2 { static constexpr int v = 1 + LOG2<X/2>::v; };
template<> struct LOG2<1> { static constexpr int v = 0; };

// ---------------------------------------------------------------------------
// Direct conv, NHWC in, HWIO weights, LDS-staged weight slices.
// Thread = NPIX pixels x 4 co. G: ci-split (FROZEN per layer — VQ argmin is
// sensitive to latent rounding; G changes accumulation order). CS: co-split
// across blocks (numerics-free). NPIX: pixels/thread (numerics-free).
// Stage-all if filter slice <= 47KB else per-ky-row. Grids EXACT.
// ---------------------------------------------------------------------------
template<int KH,int KW,int STRIDE,int PAD,int CIN,int COUT,int NPIX,
         bool ACT,bool BIAS,int G,int CS>
__global__ __launch_bounds__(256) void conv_k(
    const float* __restrict__ in, const float* __restrict__ w,
    const float* __restrict__ bias, float* __restrict__ out,
    int N,int H,int W,int OH,int OW)
{
  constexpr int CLEN = CIN/G;
  constexpr int COB  = COUT/CS;
  constexpr int COQ  = COB/4;
  constexpr int GSH  = LOG2<G>::v;
  constexpr int CSH  = LOG2<CS>::v;
  constexpr int TAPF = CLEN*COB;                 // floats per staged tap
  constexpr bool SALL = (KH*KW*TAPF*4) <= 47*1024;
  constexpr int NTAP = SALL ? KH*KW : KW;
  static_assert(CLEN==3 || (CLEN%4)==0, "ci");
  __shared__ float sw[NTAP*TAPF];

  const int g  = blockIdx.x & (G-1);
  const int cs = (blockIdx.x >> GSH) & (CS-1);
  const int bx = blockIdx.x >> (GSH+CSH);
  const int total = N*OH*OW;
  if (G>1) out += (size_t)g * total * COUT;
  const int ci_off  = g*CLEN;
  const int co_base = cs*COB;

  int idx = bx*256 + (int)threadIdx.x;
  int cq = idx % COQ;
  int pg = idx / COQ;
  int co = cq*4;                 // within block's co slice
  int gco = co_base + co;        // global co
  int p0 = pg*NPIX;

  float acc[NPIX][4] = {};
  int iy0[NPIX], ix0[NPIX]; const float* base[NPIX]; bool pv[NPIX];
#pragma unroll
  for (int t=0;t<NPIX;t++){
    int p=p0+t; pv[t]=(p<total); int pp=pv[t]?p:0;
    int ox=pp%OW; int r=pp/OW; int oy=r%OH; int n=r/OH;
    iy0[t]=oy*STRIDE-PAD; ix0[t]=ox*STRIDE-PAD;
    base[t]=in+(size_t)n*H*W*CIN + ci_off;
  }

  auto stage = [&](int tap0){
    constexpr int TQ = TAPF/4;
    constexpr int V  = NTAP*TQ;
    for (int v=threadIdx.x; v<V; v+=256){
      int tap = v / TQ; int rem = v - tap*TQ;
      float4 q;
      if constexpr (CS==1){
        const float4* src = (const float4*)(w + ((size_t)(tap0+tap)*CIN + ci_off)*COUT);
        q = src[rem];
      } else {
        int ci = rem / (COB/4); int r2 = rem - ci*(COB/4);
        q = *(const float4*)(w + ((size_t)(tap0+tap)*CIN + ci_off + ci)*COUT
                               + co_base + r2*4);
      }
      *(float4*)(sw + (size_t)tap*TAPF + rem*4) = q;
    }
  };

  if constexpr (SALL){
    stage(0);
    __syncthreads();
  }

  for (int ky=0; ky<KH; ky++){
    if constexpr (!SALL){
      __syncthreads();
      stage(ky*KW);
      __syncthreads();
    }
    const float* swr = SALL ? sw + (size_t)ky*KW*TAPF : sw;
    for (int kx=0; kx<KW; kx++){
      const float* swt = swr + (size_t)kx*TAPF;
      const float* ip[NPIX]; bool ok[NPIX];
#pragma unroll
      for (int t=0;t<NPIX;t++){
        int iy=iy0[t]+ky, ix=ix0[t]+kx;
        ok[t]=pv[t] && iy>=0 && iy<H && ix>=0 && ix<W;
        ip[t]=base[t]+(size_t)(iy*W+ix)*CIN;
      }
      if constexpr (CLEN==3){
        float wv[3][4];
        *(float4*)wv[0]=*(const float4*)(swt + 0*COB + co);
        *(float4*)wv[1]=*(const float4*)(swt + 1*COB + co);
        *(float4*)wv[2]=*(const float4*)(swt + 2*COB + co);
#pragma unroll
        for (int t=0;t<NPIX;t++){
          float v0=ok[t]?ip[t][0]:0.f;
          float v1=ok[t]?ip[t][1]:0.f;
          float v2=ok[t]?ip[t][2]:0.f;
#pragma unroll
          for (int j=0;j<4;j++)
            acc[t][j]=fmaf(v0,wv[0][j],fmaf(v1,wv[1][j],fmaf(v2,wv[2][j],acc[t][j])));
        }
      } else {
#pragma unroll 2
        for (int ci=0; ci<CLEN; ci+=4){
          float wv[4][4];
#pragma unroll
          for (int r=0;r<4;r++)
            *(float4*)wv[r] = *(const float4*)(swt + (ci+r)*COB + co);
#pragma unroll
          for (int t=0;t<NPIX;t++){
            float va[4];
            *(float4*)va = ok[t] ? *(const float4*)(ip[t]+ci)
                                 : make_float4(0.f,0.f,0.f,0.f);
#pragma unroll
            for (int r=0;r<4;r++)
#pragma unroll
              for (int j=0;j<4;j++)
                acc[t][j]=fmaf(va[r],wv[r][j],acc[t][j]);
          }
        }
      }
    }
  }

  float bv[4]={0.f,0.f,0.f,0.f};
  if constexpr (BIAS) *(float4*)bv = *(const float4*)(bias+gco);
#pragma unroll
  for (int t=0;t<NPIX;t++) if (pv[t]){
    float o[4];
#pragma unroll
    for (int j=0;j<4;j++){
      float v = acc[t][j]+bv[j];
      o[j] = ACT ? silu_f(v) : v;
    }
    *(float4*)(out + (size_t)(p0+t)*COUT + gco) = *(float4*)o;
  }
}

// ---------------------------------------------------------------------------
// reduce G partials (stride n) + bias + optional silu.
// ---------------------------------------------------------------------------
template<int G,int COUT,bool ACT>
__global__ __launch_bounds__(256) void reduce_k(
    const float* __restrict__ p, const float* __restrict__ bias,
    float* __restrict__ out, int n)
{
  int i = (blockIdx.x*256+threadIdx.x)*4;
  if (i>=n) return;
  float a[4]; *(float4*)a = *(const float4*)(p+i);
#pragma unroll
  for (int g=1; g<G; g++){
    float b[4]; *(float4*)b = *(const float4*)(p+(size_t)g*n+i);
#pragma unroll
    for (int j=0;j<4;j++) a[j]+=b[j];
  }
  float bv[4]; *(float4*)bv = *(const float4*)(bias + (i % COUT));
#pragma unroll
  for (int j=0;j<4;j++){
    float v=a[j]+bv[j];
    a[j] = ACT ? silu_f(v) : v;
  }
  *(float4*)(out+i) = *(float4*)a;
}

// ---------------------------------------------------------------------------
// conv_transpose 5x5 s2 SAME (verified r0 mapping), per-tap LDS weight stage.
// parity = b&3, ci-group = (b>>2)&(G-1), spatial = b>>(2+GSH).
// ---------------------------------------------------------------------------
template<int CIN,int COUT,int NPIX,int G,bool DIRECT>
__global__ __launch_bounds__(256) void tconv_k(
    const float* __restrict__ in, const float* __restrict__ w,
    const float* __restrict__ bias, float* __restrict__ out,
    int N,int H,int W,int OH,int OW)
{
  constexpr int COQ  = COUT/4;
  constexpr int CLEN = CIN/G;
  constexpr int GSH  = LOG2<G>::v;
  constexpr int TAPF = CLEN*COUT;
  __shared__ float sw[TAPF];
  const int par = blockIdx.x & 3;
  const int py = par>>1, px = par&1;
  const int g  = (blockIdx.x>>2) & (G-1);
  const int bx = blockIdx.x >> (2+GSH);
  const int NKY = py?3:2, NKX = px?3:2;
  const int OHh=OH>>1, OWh=OW>>1;
  const int total = N*OHh*OWh;
  if (G>1) out += (size_t)g * N*OH*OW*COUT;

  int idx = bx*256 + (int)threadIdx.x;
  int cq = idx % COQ;
  int pg = idx / COQ;
  int co = cq*4;
  int p0 = pg*NPIX;

  float acc[NPIX][4] = {};
  int yy[NPIX], xx[NPIX], nn[NPIX]; const float* base[NPIX]; bool pv[NPIX];
#pragma unroll
  for (int t=0;t<NPIX;t++){
    int p=p0+t; pv[t]=(p<total); int pp=pv[t]?p:0;
    xx[t]=pp%OWh; int r=pp/OWh; yy[t]=r%OHh; nn[t]=r/OHh;
    base[t]=in+(size_t)nn[t]*H*W*CIN + g*CLEN;
  }

  for (int j=0;j<NKY;j++){
    int ky = 2*j + (py?0:1);
    for (int i=0;i<NKX;i++){
      int kx = 2*i + (px?0:1);
      __syncthreads();
      {
        constexpr int V = TAPF/4;
        const float4* src = (const float4*)(w + ((size_t)(ky*5+kx)*CIN + g*CLEN)*COUT);
        for (int v=threadIdx.x; v<V; v+=256) ((float4*)sw)[v]=src[v];
      }
      __syncthreads();
      const float* ip[NPIX]; bool ok[NPIX];
#pragma unroll
      for (int t=0;t<NPIX;t++){
        int iy=yy[t]+j-1, ix=xx[t]+i-1;
        ok[t]=pv[t] && iy>=0 && iy<H && ix>=0 && ix<W;
        ip[t]=base[t]+(size_t)(iy*W+ix)*CIN;
      }
#pragma unroll 2
      for (int ci=0; ci<CLEN; ci+=4){
        float wv[4][4];
#pragma unroll
        for (int r=0;r<4;r++)
          *(float4*)wv[r] = *(const float4*)(sw + (ci+r)*COUT + co);
#pragma unroll
        for (int t=0;t<NPIX;t++){
          float va[4];
          *(float4*)va = ok[t] ? *(const float4*)(ip[t]+ci)
                               : make_float4(0.f,0.f,0.f,0.f);
#pragma unroll
          for (int r=0;r<4;r++)
#pragma unroll
            for (int jj=0;jj<4;jj++)
              acc[t][jj]=fmaf(va[r],wv[r][jj],acc[t][jj]);
        }
      }
    }
  }

  float bv[4]={0.f,0.f,0.f,0.f};
  if constexpr (DIRECT) *(float4*)bv = *(const float4*)(bias+co);
#pragma unroll
  for (int t=0;t<NPIX;t++) if (pv[t]){
    float o[4];
#pragma unroll
    for (int jj=0;jj<4;jj++){
      float v = acc[t][jj]+bv[jj];
      o[jj] = DIRECT ? silu_f(v) : v;
    }
    *(float4*)(out + (((size_t)nn[t]*OH + (2*yy[t]+py))*OW + (2*xx[t]+px))*COUT + co) = *(float4*)o;
  }
}

// ---------------------------------------------------------------------------
// VQ fused with conv3c 2-partial reduction + bias (round-2 EXACT — FROZEN).
// ---------------------------------------------------------------------------
__global__ __launch_bounds__(256) void vq_k(
    const float* __restrict__ p, const float* __restrict__ bias,
    const float* __restrict__ cb, float* __restrict__ q, int NLat)
{
  __shared__ float slat[4][128];
  int wave = threadIdx.x >> 6;
  int lane = threadIdx.x & 63;
  int l = blockIdx.x*4 + wave;
  if (l >= NLat) return;
  const float* p0 = p + (size_t)l*128;
  const float* p1 = p0 + (size_t)NLat*128;
  slat[wave][lane]    = p0[lane]    + p1[lane]    + bias[lane];
  slat[wave][lane+64] = p0[lane+64] + p1[lane+64] + bias[lane+64];

  float bestd = INFINITY; int besti = 0;
  for (int c0=0;c0<256;c0+=64){
    int c = c0 + lane;
    const float* cp = cb + (size_t)c*128;
    float d = 0.f;
#pragma unroll 8
    for (int k=0;k<128;k+=4){
      float4 cv = *reinterpret_cast<const float4*>(cp+k);
      float d0 = slat[wave][k+0]-cv.x;
      float d1 = slat[wave][k+1]-cv.y;
      float d2 = slat[wave][k+2]-cv.z;
      float d3 = slat[wave][k+3]-cv.w;
      d += d0*d0; d += d1*d1; d += d2*d2; d += d3*d3;
    }
    if (d < bestd) { bestd = d; besti = c; }
  }
  for (int off=32; off; off>>=1){
    float od = __shfl_down(bestd, off);
    int   oi = __shfl_down(besti, off);
    if (od < bestd || (od == bestd && oi < besti)) { bestd=od; besti=oi; }
  }
  besti = __shfl(besti, 0);
  const float* cp = cb + (size_t)besti*128;
  float* qp = q + (size_t)l*128;
  qp[lane]    = cp[lane];
  qp[lane+64] = cp[lane+64];
}

// ---------------------------------------------------------------------------
// Final 3x3 conv 32->3 split over ky rows (g = blockIdx%3). Writes partials.
// ---------------------------------------------------------------------------
__global__ __launch_bounds__(256) void conv_last_k(
    const float* __restrict__ in, const float* __restrict__ w,
    float* __restrict__ p, int N,int H,int W)
{
  int g = blockIdx.x % 3;
  int bx = blockIdx.x / 3;
  int pix = bx*256 + threadIdx.x;
  int total = N*H*W;
  if (pix>=total) return;
  int x = pix % W; int r = pix / W; int y = r % H; int n = r / H;
  float a0=0.f, a1=0.f, a2=0.f;
  int iy = y + g - 1;
  if (iy>=0 && iy<H){
    const float* base = in + ((size_t)n*H + iy)*W*32;
    for (int kx=0;kx<3;kx++){
      int ix=x+kx-1; if(ix<0||ix>=W) continue;
      const float* ip = base + (size_t)ix*32;
      const float* wp = w + (size_t)((g*3+kx)*32)*3;
#pragma unroll
      for (int ci=0;ci<32;ci+=4){
        float va[4]; *(float4*)va = *(const float4*)(ip+ci);
        float wv[12];
        *(float4*)(wv+0) = *(const float4*)(wp+ci*3+0);
        *(float4*)(wv+4) = *(const float4*)(wp+ci*3+4);
        *(float4*)(wv+8) = *(const float4*)(wp+ci*3+8);
#pragma unroll
        for (int r2=0;r2<4;r2++){
          a0 = fmaf(va[r2], wv[r2*3+0], a0);
          a1 = fmaf(va[r2], wv[r2*3+1], a1);
          a2 = fmaf(va[r2], wv[r2*3+2], a2);
        }
      }
    }
  }
  float* pp = p + (size_t)g*total*3 + (size_t)pix*3;
  pp[0]=a0; pp[1]=a1; pp[2]=a2;
}

__global__ __launch_bounds__(256) void reduce_last_k(
    const float* __restrict__ p, const float* __restrict__ bias,
    float* __restrict__ out, int n)
{
  int i = (blockIdx.x*256+threadIdx.x)*4;
  if (i>=n) return;
  float a[4]; *(float4*)a = *(const float4*)(p+i);
#pragma unroll
  for (int g=1; g<3; g++){
    float b[4]; *(float4*)b = *(const float4*)(p+(size_t)g*n+i);
#pragma unroll
    for (int j=0;j<4;j++) a[j]+=b[j];
  }
  float o[4];
#pragma unroll
  for (int j=0;j<4;j++) o[j] = a[j] + bias[(i+j)%3];
  *(float4*)(out+i) = *(float4*)o;
}

extern "C" void kernel_launch(void* const* d_in, const int* in_sizes, int n_in,
                              void* d_out, int out_size, void* d_ws, size_t ws_size,
                              hipStream_t stream) {
  const float* x    = (const float*)d_in[0];
  const float* k1   = (const float*)d_in[1];  const float* b1  = (const float*)d_in[2];
  const float* k1c  = (const float*)d_in[3];  const float* b1c = (const float*)d_in[4];
  const float* k2   = (const float*)d_in[5];  const float* b2  = (const float*)d_in[6];
  const float* k2c  = (const float*)d_in[7];  const float* b2c = (const float*)d_in[8];
  const float* k3   = (const float*)d_in[9];  const float* b3  = (const float*)d_in[10];
  const float* k3c  = (const float*)d_in[11]; const float* b3c = (const float*)d_in[12];
  const float* cb   = (const float*)d_in[13];
  const float* tk1  = (const float*)d_in[14]; const float* tb1  = (const float*)d_in[15];
  const float* tk1c = (const float*)d_in[16]; const float* tb1c = (const float*)d_in[17];
  const float* tk2  = (const float*)d_in[18]; const float* tb2  = (const float*)d_in[19];
  const float* tk2c = (const float*)d_in[20]; const float* tb2c = (const float*)d_in[21];
  const float* tk3  = (const float*)d_in[22]; const float* tb3  = (const float*)d_in[23];
  const float* tk3c = (const float*)d_in[24]; const float* tb3c = (const float*)d_in[25];
  float* out = (float*)d_out;

  float* S  = (float*)d_ws;
  float* W0 = S;                 // [0 .. 1M) floats
  float* W1 = S + 1048576;       // [1M .. 2M)
  float* P  = S + 2097152;       // [2M .. 6M)
  dim3 blk(256);

  // ---- encoder: G-splits + fmaf order FROZEN to r6/r7 (VQ argmin) ----
  // conv1 11x11 s2 3->32: G1 CS2 (stage-all 23.2KB), NPIX=1 -> 1024 blocks
  conv_k<11,11,2,4,  3, 32,1,true ,true ,1,2><<<1024,blk,0,stream>>>(x,  k1,  b1,  W0, 8,128,128,64,64);
  // conv1c 3x3 32->32 @64x64: G1 CS2 (stage-all 18KB), NPIX=1 -> 1024 blocks
  conv_k< 3, 3,1,1, 32, 32,1,true ,true ,1,2><<<1024,blk,0,stream>>>(W0, k1c, b1c, W1, 8,64,64,64,64);
  // conv2 11x11 s2 32->64: G2 CS2 (per-ky 22.5KB), NPIX=1 -> 1024 blocks
  conv_k<11,11,2,4, 32, 64,1,false,false,2,2><<<1024,blk,0,stream>>>(W1, k2,  nullptr, P, 8,64,64,32,32);
  reduce_k<2, 64,true><<< 512,blk,0,stream>>>(P, b2,  W0, 524288);
  // conv2c 3x3 64->64 @32x32: G1 CS2 (per-ky 24KB), NPIX=1 -> 512 blocks
  conv_k< 3, 3,1,1, 64, 64,1,true ,true ,1,2><<< 512,blk,0,stream>>>(W0, k2c, b2c, W1, 8,32,32,32,32);
  // conv3 11x11 s2 64->128: G4 CS4 (per-ky 22.5KB), NPIX=1 -> 1024 blocks
  conv_k<11,11,2,4, 64,128,1,false,false,4,4><<<1024,blk,0,stream>>>(W1, k3,  nullptr, P, 8,32,32,16,16);
  reduce_k<4,128,true><<< 256,blk,0,stream>>>(P, b3,  W0, 262144);
  // conv3c 3x3 128->128 @16x16: G2 CS4 (per-ky 24KB), NPIX=1 -> 512 blocks
  conv_k< 3, 3,1,1,128,128,1,false,false,2,4><<< 512,blk,0,stream>>>(W0, k3c, nullptr, P, 8,16,16,16,16);
  // ---- VQ: r2-exact 2-partial reduce + argmin + gather (FROZEN) ----
  vq_k<<<512,blk,0,stream>>>(P, b3c, cb, W1, 2048);
  // ---- decoder (G frozen; staging/NPIX numerics-free) ----
  // tconv1 5x5 s2 128->64: G4, per-tap 8KB, NPIX=1 -> 2048 blocks
  tconv_k<128,64,1,4,false><<<2048,blk,0,stream>>>(W1, tk1, nullptr, P, 8,16,16,32,32);
  reduce_k<4, 64,true><<< 512,blk,0,stream>>>(P, tb1,  W0, 524288);
  // tk1c 3x3 64->64 @32x32: G2 CS2 (per-ky 12KB), NPIX=1 -> 1024 blocks
  conv_k< 3, 3,1,1, 64, 64,1,false,false,2,2><<<1024,blk,0,stream>>>(W0, tk1c, nullptr, P, 8,32,32,32,32);
  reduce_k<2, 64,true><<< 512,blk,0,stream>>>(P, tb1c, W1, 524288);
  // tconv2 5x5 s2 64->32: G2, per-tap 4KB, NPIX=1 -> 2048 blocks
  tconv_k< 64,32,1,2,false><<<2048,blk,0,stream>>>(W1, tk2, nullptr, P, 8,32,32,64,64);
  reduce_k<2, 32,true><<<1024,blk,0,stream>>>(P, tb2,  W0, 1048576);
  // tk2c 3x3 32->32 @64x64: G1 CS2 (stage-all 18KB), NPIX=1 -> 1024 blocks
  conv_k< 3, 3,1,1, 32, 32,1,true ,true ,1,2><<<1024,blk,0,stream>>>(W0, tk2c, tb2c, W1, 8,64,64,64,64);
  // tconv3 5x5 s2 32->32: G1, per-tap 4KB, NPIX=2 -> 2048 blocks (keep)
  tconv_k< 32,32,2,1,true ><<<2048,blk,0,stream>>>(W1, tk3, tb3, P, 8,64,64,128,128);
  // conv_last 3x3 32->3: ky-split g=b%3, 1536 blocks + reduce
  conv_last_k<<<1536,blk,0,stream>>>(P, tk3c, S, 8,128,128);
  reduce_last_k<<<384,blk,0,stream>>>(S, tb3c, out, 393216);
}